// Round 12
// baseline (1093.165 us; speedup 1.0000x reference)
//
#include <hip/hip_runtime.h>
#include <math.h>

namespace {

constexpr int NF   = 256;   // n_feature / tokens
constexpr int EH   = 128;   // embedder hidden
constexpr int E    = 64;    // embedded dim
constexpr int H    = 64;    // lstm size
constexpr int SHD  = 256;   // shared hidden
constexpr int SD   = 128;   // shared dim
constexpr int NA   = 257;   // n_action
constexpr int NSHUF = 4;

__device__ __forceinline__ float fsig(float x) {
  return 1.f / (1.f + __expf(-x));
}
__device__ __forceinline__ float ftanh(float x) {
  return 1.f - 2.f / (__expf(2.f * x) + 1.f);
}

// Factored attention (r11, verified correct): emb = h@We2 + be2 is linear, so
//   logits = h.(We2 qt) (+const, cancels in softmax);  attended = (sum w h)@We2 + be2.
// ALLOCATOR (5-point model): declared cap -> lands one tier below.
//   (512,2) -> 128 VGPR: too tight for h-resident live set (~115) -> r11 spilled 1 GB.
//   (512) alone -> cap 512 -> lands 256: h fits with margin, zero spill, 1 blk/CU.
__global__ __launch_bounds__(512)
void seqnet(
    const float* __restrict__ state, const int* __restrict__ acquired,
    const float* __restrict__ We1, const float* __restrict__ be1,
    const float* __restrict__ We2, const float* __restrict__ be2,
    const float* __restrict__ Wih, const float* __restrict__ Whh,
    const float* __restrict__ bih, const float* __restrict__ bhh,
    const float* __restrict__ Ws1, const float* __restrict__ bs1,
    const float* __restrict__ Ws2, const float* __restrict__ bs2,
    const float* __restrict__ Wp1, const float* __restrict__ bp1,
    const float* __restrict__ Wp2, const float* __restrict__ bp2,
    const float* __restrict__ Wv1, const float* __restrict__ bv1,
    const float* __restrict__ Wv2, const float* __restrict__ bv2,
    float* __restrict__ out)
{
  const int b    = blockIdx.x;
  const int t    = threadIdx.x;   // 0..511
  const int lane = t & 63;
  const int wid  = t >> 6;        // 0..7

  __shared__ int   id_l[NF];
  __shared__ __align__(16) float val_l[NF];
  __shared__ __align__(16) float w_s[NF];          // logits
  __shared__ __align__(16) float r_s[EH];          // r = We2 @ qt
  __shared__ __align__(16) float u_s[EH];          // u = sum_t w_t h_t
  __shared__ __align__(16) float partial[8][EH];   // per-wave u partials
  __shared__ __align__(16) float red_s[512];
  __shared__ __align__(16) float t1_s[SHD];
  __shared__ __align__(16) float sh_s[SD];
  __shared__ __align__(16) float a1_s[SD];
  __shared__ __align__(16) float v1_s[SD];
  __shared__ int   wcnt[4];
  __shared__ float wred[8];
  __shared__ __align__(16) float qt_s[H];
  __shared__ float ct_s[H];
  __shared__ __align__(16) float att_s[E];
  __shared__ float v_scalar;

  // ---------------- phase 0: closed-form "argsort" ----------------
  int ai = 0, pin = 0;
  if (t < NF) {
    id_l[t] = 0; val_l[t] = 0.f;                   // tok >= L defaults
    ai = (acquired[b * NF + t] != 0) ? 1 : 0;
    const unsigned long long mask = __ballot(ai);
    pin = __popcll(mask & ((1ull << lane) - 1ull));
    if (lane == 0) wcnt[wid] = __popcll(mask);     // wid 0..3 here
  }
  if (t < H) { qt_s[t] = 0.f; ct_s[t] = 0.f; att_s[t] = 0.f; }
  __syncthreads();
  const int L = wcnt[0] + wcnt[1] + wcnt[2] + wcnt[3];
  if (t < NF && ai) {
    int pexcl = pin;
    #pragma unroll
    for (int w = 0; w < 4; ++w) if (w < wid) pexcl += wcnt[w];
    const int rank = L - pexcl - 1;                // # acquired with index > t
    id_l[rank]  = t + 1;
    val_l[rank] = state[b * NF + t];
  }
  __syncthreads();

  // ---------------- phase 1: h in registers ----------------
  // thread owns tokens {tg, tg+128}, k-slice [ksf, ksf+32).
  // h[tok][k] = relu(val*We1[0][k] + We1[id][k] + be1[k])
  const int tg   = t >> 2;
  const int ksf  = (t & 3) * 32;
  const int tok0 = tg, tok1 = tg + 128;
  float4 h0[8], h1[8];
  {
    const int   id0 = id_l[tok0]; const float v0 = val_l[tok0];
    const int   id1 = id_l[tok1]; const float v1 = val_l[tok1];
    const float4* __restrict__ g0 = (const float4*)(We1 + id0 * EH + ksf);
    const float4* __restrict__ g1 = (const float4*)(We1 + id1 * EH + ksf);
    const float4* __restrict__ z  = (const float4*)(We1 + ksf);   // row 0
    const float4* __restrict__ bb = (const float4*)(be1 + ksf);
    #pragma unroll
    for (int j = 0; j < 8; ++j) {
      const float4 zz = z[j], dd = bb[j];
      const float4 a = g0[j];
      h0[j].x = fmaxf(fmaf(v0, zz.x, a.x) + dd.x, 0.f);
      h0[j].y = fmaxf(fmaf(v0, zz.y, a.y) + dd.y, 0.f);
      h0[j].z = fmaxf(fmaf(v0, zz.z, a.z) + dd.z, 0.f);
      h0[j].w = fmaxf(fmaf(v0, zz.w, a.w) + dd.w, 0.f);
      const float4 c = g1[j];
      h1[j].x = fmaxf(fmaf(v1, zz.x, c.x) + dd.x, 0.f);
      h1[j].y = fmaxf(fmaf(v1, zz.y, c.y) + dd.y, 0.f);
      h1[j].z = fmaxf(fmaf(v1, zz.z, c.z) + dd.z, 0.f);
      h1[j].w = fmaxf(fmaf(v1, zz.w, c.w) + dd.w, 0.f);
    }
  }

  // ---------------- phase 2: factored attention + LSTM ----------------
  if (L > 0) {
    const float invL = 1.f / (float)L;
    for (int it = 0; it < NSHUF; ++it) {
      float w0, w1;
      if (it == 0) {
        // qt == 0 -> uniform softmax over first L tokens
        w0 = (tok0 < L) ? invL : 0.f;
        w1 = (tok1 < L) ? invL : 0.f;
      } else {
        // r = We2 @ qt (row k of We2 is contiguous)
        if (t < EH) {
          const float* __restrict__ wr = We2 + t * E;
          float x0 = 0.f, x1 = 0.f, x2 = 0.f, x3 = 0.f;
          #pragma unroll
          for (int e = 0; e < E; e += 4) {
            const float4 q = *(const float4*)(qt_s + e);
            x0 = fmaf(wr[e],     q.x, x0);
            x1 = fmaf(wr[e + 1], q.y, x1);
            x2 = fmaf(wr[e + 2], q.z, x2);
            x3 = fmaf(wr[e + 3], q.w, x3);
          }
          r_s[t] = (x0 + x1) + (x2 + x3);
        }
        __syncthreads();
        // logits: l = h . r over this thread's k-slice; reduce 4 lanes
        const float4* __restrict__ rr = (const float4*)(r_s + ksf);
        float l0 = 0.f, l1 = 0.f;
        #pragma unroll
        for (int j = 0; j < 8; ++j) {
          const float4 rj = rr[j];
          l0 = fmaf(h0[j].x, rj.x, fmaf(h0[j].y, rj.y,
               fmaf(h0[j].z, rj.z, fmaf(h0[j].w, rj.w, l0))));
          l1 = fmaf(h1[j].x, rj.x, fmaf(h1[j].y, rj.y,
               fmaf(h1[j].z, rj.z, fmaf(h1[j].w, rj.w, l1))));
        }
        l0 += __shfl_xor(l0, 1); l0 += __shfl_xor(l0, 2);
        l1 += __shfl_xor(l1, 1); l1 += __shfl_xor(l1, 2);
        if ((t & 3) == 0) { w_s[tg] = l0; w_s[tg + 128] = l1; }
        __syncthreads();
        // block softmax stats, computed redundantly per wave (no extra barriers)
        float x0 = (lane       < L) ? w_s[lane]       : -1e30f;
        float x1 = (lane +  64 < L) ? w_s[lane +  64] : -1e30f;
        float x2 = (lane + 128 < L) ? w_s[lane + 128] : -1e30f;
        float x3 = (lane + 192 < L) ? w_s[lane + 192] : -1e30f;
        float m = fmaxf(fmaxf(x0, x1), fmaxf(x2, x3));
        #pragma unroll
        for (int d = 32; d > 0; d >>= 1) m = fmaxf(m, __shfl_xor(m, d));
        float s = __expf(x0 - m) + __expf(x1 - m) + __expf(x2 - m) + __expf(x3 - m);
        #pragma unroll
        for (int d = 32; d > 0; d >>= 1) s += __shfl_xor(s, d);
        const float inv_s = 1.f / s;
        w0 = (tok0 < L) ? __expf(l0 - m) * inv_s : 0.f;
        w1 = (tok1 < L) ? __expf(l1 - m) * inv_s : 0.f;
      }

      // u = sum_t w_t h_t : register partial + 16-lane tree + 8-wave combine
      {
        float4 u[8];
        #pragma unroll
        for (int j = 0; j < 8; ++j) {
          u[j].x = fmaf(w0, h0[j].x, w1 * h1[j].x);
          u[j].y = fmaf(w0, h0[j].y, w1 * h1[j].y);
          u[j].z = fmaf(w0, h0[j].z, w1 * h1[j].z);
          u[j].w = fmaf(w0, h0[j].w, w1 * h1[j].w);
        }
        #pragma unroll
        for (int d = 4; d <= 32; d <<= 1) {
          #pragma unroll
          for (int j = 0; j < 8; ++j) {
            u[j].x += __shfl_xor(u[j].x, d);
            u[j].y += __shfl_xor(u[j].y, d);
            u[j].z += __shfl_xor(u[j].z, d);
            u[j].w += __shfl_xor(u[j].w, d);
          }
        }
        if (lane < 4) {
          #pragma unroll
          for (int j = 0; j < 8; ++j)
            *(float4*)&partial[wid][lane * 32 + j * 4] = u[j];
        }
      }
      __syncthreads();
      if (t < EH) {
        float s0 = 0.f;
        #pragma unroll
        for (int q = 0; q < 8; ++q) s0 += partial[q][t];
        u_s[t] = s0;
      }
      __syncthreads();

      // attended = u @ We2 + be2 (64 threads, coalesced column reads)
      if (t < E) {
        const float* __restrict__ col = We2 + t;     // stride E
        float x0 = 0.f, x1 = 0.f, x2 = 0.f, x3 = 0.f;
        #pragma unroll
        for (int k = 0; k < EH; k += 4) {
          x0 = fmaf(u_s[k],     col[(k)     * E], x0);
          x1 = fmaf(u_s[k + 1], col[(k + 1) * E], x1);
          x2 = fmaf(u_s[k + 2], col[(k + 2) * E], x2);
          x3 = fmaf(u_s[k + 3], col[(k + 3) * E], x3);
        }
        att_s[t] = (x0 + x1) + (x2 + x3) + be2[t];
      }
      __syncthreads();

      // gates: waves 0-3: att@Wih, waves 4-7: qt@Whh (qt=0 at it0 -> 0)
      {
        const int col = t & 255;
        const int hf  = t >> 8;
        const float* __restrict__ W = hf ? Whh : Wih;
        const float* __restrict__ x = hf ? qt_s : att_s;
        float g0 = 0.f, g1 = 0.f, g2 = 0.f, g3 = 0.f;
        #pragma unroll
        for (int e = 0; e < 64; e += 4) {
          const float4 q = *(const float4*)(x + e);
          g0 = fmaf(q.x, W[(e)     * 256 + col], g0);
          g1 = fmaf(q.y, W[(e + 1) * 256 + col], g1);
          g2 = fmaf(q.z, W[(e + 2) * 256 + col], g2);
          g3 = fmaf(q.w, W[(e + 3) * 256 + col], g3);
        }
        red_s[t] = (g0 + g1) + (g2 + g3);
      }
      __syncthreads();
      if (t < H) {   // fused halves-combine + bias + LSTM cell
        const float ig = red_s[t]       + red_s[256 + t]       + bih[t]       + bhh[t];
        const float fg = red_s[64 + t]  + red_s[320 + t]       + bih[64 + t]  + bhh[64 + t];
        const float gg = red_s[128 + t] + red_s[384 + t]       + bih[128 + t] + bhh[128 + t];
        const float og = red_s[192 + t] + red_s[448 + t]       + bih[192 + t] + bhh[192 + t];
        float c = ct_s[t];
        c = fsig(fg) * c + fsig(ig) * ftanh(gg);
        ct_s[t] = c;
        qt_s[t] = fsig(og) * ftanh(c);
      }
      __syncthreads();
    }
  }

  // ---------------- phase 3: DuelingNet (r10 verbatim) ----------------
  {
    const int col = t & 255;
    const int hf  = t >> 8;
    const float* __restrict__ x = hf ? qt_s : att_s;
    const float* __restrict__ W = Ws1 + hf * 64 * SHD;
    float x0 = 0.f, x1 = 0.f, x2 = 0.f, x3 = 0.f;
    #pragma unroll
    for (int k = 0; k < 64; k += 4) {
      const float4 q = *(const float4*)(x + k);
      x0 = fmaf(q.x, W[(k)     * SHD + col], x0);
      x1 = fmaf(q.y, W[(k + 1) * SHD + col], x1);
      x2 = fmaf(q.z, W[(k + 2) * SHD + col], x2);
      x3 = fmaf(q.w, W[(k + 3) * SHD + col], x3);
    }
    red_s[t] = (x0 + x1) + (x2 + x3);
  }
  __syncthreads();
  if (t < SHD) t1_s[t] = fmaxf(red_s[t] + red_s[256 + t] + bs1[t], 0.f);
  __syncthreads();
  {
    const int col = t & 127;
    const int qq  = t >> 7;
    const float* __restrict__ xq = t1_s + qq * 64;
    float x0 = 0.f, x1 = 0.f, x2 = 0.f, x3 = 0.f;
    #pragma unroll
    for (int k = 0; k < 64; k += 4) {
      const float4 q = *(const float4*)(xq + k);
      x0 = fmaf(q.x, Ws2[(qq * 64 + k)     * SD + col], x0);
      x1 = fmaf(q.y, Ws2[(qq * 64 + k + 1) * SD + col], x1);
      x2 = fmaf(q.z, Ws2[(qq * 64 + k + 2) * SD + col], x2);
      x3 = fmaf(q.w, Ws2[(qq * 64 + k + 3) * SD + col], x3);
    }
    red_s[t] = (x0 + x1) + (x2 + x3);
  }
  __syncthreads();
  if (t < SD)
    sh_s[t] = fmaxf((red_s[t] + red_s[128 + t]) + (red_s[256 + t] + red_s[384 + t]) + bs2[t], 0.f);
  __syncthreads();
  {
    const int col  = t & 127;
    const int half = (t >> 7) & 1;
    const int net  = t >> 8;
    const float* __restrict__ W  = (net ? Wv1 : Wp1) + half * 64 * SD;
    const float* __restrict__ xh = sh_s + half * 64;
    float x0 = 0.f, x1 = 0.f, x2 = 0.f, x3 = 0.f;
    #pragma unroll
    for (int k = 0; k < 64; k += 4) {
      const float4 q = *(const float4*)(xh + k);
      x0 = fmaf(q.x, W[(k)     * SD + col], x0);
      x1 = fmaf(q.y, W[(k + 1) * SD + col], x1);
      x2 = fmaf(q.z, W[(k + 2) * SD + col], x2);
      x3 = fmaf(q.w, W[(k + 3) * SD + col], x3);
    }
    red_s[t] = (x0 + x1) + (x2 + x3);
  }
  __syncthreads();
  if (t < SD) {
    a1_s[t] = fmaxf(red_s[t] + red_s[128 + t] + bp1[t], 0.f);
  } else if (t < 2 * SD) {
    const int tt = t - SD;
    v1_s[tt] = fmaxf(red_s[256 + tt] + red_s[384 + tt] + bv1[tt], 0.f);
  }
  __syncthreads();
  if (wid == 7) {
    float vv = fmaf(v1_s[lane], Wv2[lane], v1_s[lane + 64] * Wv2[lane + 64]);
    #pragma unroll
    for (int d = 32; d > 0; d >>= 1) vv += __shfl_xor(vv, d);
    if (lane == 0) v_scalar = vv + bv2[0];
  }
  float adv = 0.f;
  if (t < NA) {
    float x0 = 0.f, x1 = 0.f, x2 = 0.f, x3 = 0.f;
    #pragma unroll
    for (int k = 0; k < SD; k += 4) {
      const float4 a = *(const float4*)(a1_s + k);
      x0 = fmaf(a.x, Wp2[(k)     * NA + t], x0);
      x1 = fmaf(a.y, Wp2[(k + 1) * NA + t], x1);
      x2 = fmaf(a.z, Wp2[(k + 2) * NA + t], x2);
      x3 = fmaf(a.w, Wp2[(k + 3) * NA + t], x3);
    }
    adv = bp2[t] + (x0 + x1) + (x2 + x3);
  }
  float ss = adv;                       // 0 for t >= NA
  #pragma unroll
  for (int d = 32; d > 0; d >>= 1) ss += __shfl_xor(ss, d);
  if (lane == 0) wred[wid] = ss;
  __syncthreads();
  const float mean = ((wred[0] + wred[1]) + (wred[2] + wred[3]) +
                      (wred[4] + wred[5]) + (wred[6] + wred[7])) * (1.f / (float)NA);
  if (t < NA) out[b * NA + t] = v_scalar + adv - mean;
}

}  // namespace

extern "C" void kernel_launch(void* const* d_in, const int* in_sizes, int n_in,
                              void* d_out, int out_size, void* d_ws, size_t ws_size,
                              hipStream_t stream) {
  const float* state    = (const float*)d_in[0];
  const int*   acquired = (const int*)d_in[1];
  const float* We1 = (const float*)d_in[2];
  const float* be1 = (const float*)d_in[3];
  const float* We2 = (const float*)d_in[4];
  const float* be2 = (const float*)d_in[5];
  const float* Wih = (const float*)d_in[6];
  const float* Whh = (const float*)d_in[7];
  const float* bih = (const float*)d_in[8];
  const float* bhh = (const float*)d_in[9];
  const float* Ws1 = (const float*)d_in[10];
  const float* bs1 = (const float*)d_in[11];
  const float* Ws2 = (const float*)d_in[12];
  const float* bs2 = (const float*)d_in[13];
  const float* Wp1 = (const float*)d_in[14];
  const float* bp1 = (const float*)d_in[15];
  const float* Wp2 = (const float*)d_in[16];
  const float* bp2 = (const float*)d_in[17];
  const float* Wv1 = (const float*)d_in[18];
  const float* bv1 = (const float*)d_in[19];
  const float* Wv2 = (const float*)d_in[20];
  const float* bv2 = (const float*)d_in[21];
  float* out = (float*)d_out;

  const int Bn = in_sizes[0] / NF;   // 2048
  hipLaunchKernelGGL(seqnet, dim3(Bn), dim3(512), 0, stream,
                     state, acquired, We1, be1, We2, be2, Wih, Whh, bih, bhh,
                     Ws1, bs1, Ws2, bs2, Wp1, bp1, Wp2, bp2, Wv1, bv1, Wv2, bv2,
                     out);
}

// Round 13
// 621.447 us; speedup vs baseline: 1.7591x; 1.7591x over previous
//
#include <hip/hip_runtime.h>
#include <math.h>

namespace {

constexpr int NF   = 256;   // n_feature / tokens
constexpr int EH   = 128;   // embedder hidden
constexpr int E    = 64;    // embedded dim
constexpr int H    = 64;    // lstm size
constexpr int SHD  = 256;   // shared hidden
constexpr int SD   = 128;   // shared dim
constexpr int NA   = 257;   // n_action
constexpr int NSHUF = 4;

__device__ __forceinline__ float fsig(float x) {
  return 1.f / (1.f + __expf(-x));
}
__device__ __forceinline__ float ftanh(float x) {
  return 1.f - 2.f / (__expf(2.f * x) + 1.f);
}

// ALLOCATOR MODEL (6-point fit, r2-r12): hipcc lands at HALF the declared cap
// (cap = 512 / min_waves_per_EU; default min_waves = ceil(waves_per_block/4)).
//   (256,4)->64  wpe(4)->64  (512,2)->128  (512)->128  (256)->256  => (256,2)->128.
// Design: factored attention with h RECOMPUTED (2 FMA + L2 gather per element),
// so nothing big is register- or LDS-resident. 256-thr blocks, ~12 KB LDS,
// 128 VGPR => 4 blocks x 4 waves = 16 waves/CU, barriers sync only 4 waves.
__global__ __launch_bounds__(256, 2)
void seqnet(
    const float* __restrict__ state, const int* __restrict__ acquired,
    const float* __restrict__ We1, const float* __restrict__ be1,
    const float* __restrict__ We2, const float* __restrict__ be2,
    const float* __restrict__ Wih, const float* __restrict__ Whh,
    const float* __restrict__ bih, const float* __restrict__ bhh,
    const float* __restrict__ Ws1, const float* __restrict__ bs1,
    const float* __restrict__ Ws2, const float* __restrict__ bs2,
    const float* __restrict__ Wp1, const float* __restrict__ bp1,
    const float* __restrict__ Wp2, const float* __restrict__ bp2,
    const float* __restrict__ Wv1, const float* __restrict__ bv1,
    const float* __restrict__ Wv2, const float* __restrict__ bv2,
    float* __restrict__ out)
{
  const int b    = blockIdx.x;
  const int t    = threadIdx.x;   // 0..255
  const int lane = t & 63;
  const int wid  = t >> 6;        // 0..3

  __shared__ int   id_l[NF];
  __shared__ __align__(16) float val_l[NF];
  __shared__ __align__(16) float w_s[NF];          // logits, then softmax w
  __shared__ __align__(16) float r_s[EH];          // r = We2 @ qt
  __shared__ __align__(16) float u_s[EH];          // u = sum_t w_t h_t
  __shared__ __align__(16) float part2[2][EH];     // u chunk partials
  __shared__ __align__(16) float red_s[NF];        // attended quarters
  __shared__ __align__(16) float gates_s[4 * H];
  __shared__ __align__(16) float t1_s[SHD];
  __shared__ __align__(16) float sh_s[SD];
  __shared__ __align__(16) float a1_s[SD];
  __shared__ __align__(16) float v1_s[SD];
  __shared__ int   wcnt[4];
  __shared__ float wred[4];
  __shared__ __align__(16) float qt_s[H];
  __shared__ float ct_s[H];
  __shared__ __align__(16) float att_s[E];
  __shared__ float v_scalar;

  // ---------------- phase 0: closed-form "argsort" (r1-verified) ----------
  id_l[t] = 0; val_l[t] = 0.f;                     // tok >= L defaults
  const int ai = (acquired[b * NF + t] != 0) ? 1 : 0;
  const unsigned long long mask = __ballot(ai);
  const int pin = __popcll(mask & ((1ull << lane) - 1ull));
  if (lane == 0) wcnt[wid] = __popcll(mask);
  if (t < H) { qt_s[t] = 0.f; ct_s[t] = 0.f; att_s[t] = 0.f; }
  __syncthreads();
  int pexcl = pin;
  int L = 0;
  #pragma unroll
  for (int w = 0; w < 4; ++w) {
    const int c = wcnt[w];
    if (w < wid) pexcl += c;
    L += c;
  }
  if (ai) {
    const int rank = L - pexcl - 1;                // # acquired with index > t
    id_l[rank]  = t + 1;
    val_l[rank] = state[b * NF + t];
  }
  __syncthreads();

  // ---------------- phase 2: factored attention + LSTM (h recomputed) -----
  if (L > 0) {
    const float invL = 1.f / (float)L;
    const int   k_u  = t & 127;                    // u-pass column
    const int   ch_u = t >> 7;                     // u-pass token chunk
    const float zk_u = We1[k_u];                   // hoisted row-0 weight
    const float bk_u = be1[k_u];                   // hoisted bias
    for (int it = 0; it < NSHUF; ++it) {
      if (it == 0) {
        // qt == 0 -> uniform softmax over first L tokens
        w_s[t] = (t < L) ? invL : 0.f;
        __syncthreads();
      } else {
        // r = We2 @ qt  (row k of We2 contiguous; t < 128 active)
        if (t < EH) {
          const float* __restrict__ wr = We2 + t * E;
          float x0 = 0.f, x1 = 0.f, x2 = 0.f, x3 = 0.f;
          #pragma unroll
          for (int e = 0; e < E; e += 4) {
            const float4 q = *(const float4*)(qt_s + e);
            x0 = fmaf(wr[e],     q.x, x0);
            x1 = fmaf(wr[e + 1], q.y, x1);
            x2 = fmaf(wr[e + 2], q.z, x2);
            x3 = fmaf(wr[e + 3], q.w, x3);
          }
          r_s[t] = (x0 + x1) + (x2 + x3);
        }
        __syncthreads();
        // logits: token t, h recomputed on the fly, dot with r
        float l0 = 0.f, l1 = 0.f, l2 = 0.f, l3 = 0.f;
        {
          const float* __restrict__ g = We1 + id_l[t] * EH;
          const float vt = val_l[t];
          #pragma unroll 2
          for (int j = 0; j < EH; j += 16) {
            #pragma unroll
            for (int q = 0; q < 4; ++q) {
              const int jj = j + q * 4;
              const float4 ga = *(const float4*)(g + jj);
              const float4 za = *(const float4*)(We1 + jj);
              const float4 ba = *(const float4*)(be1 + jj);
              const float4 ra = *(const float4*)(r_s + jj);
              const float h0 = fmaxf(fmaf(vt, za.x, ga.x) + ba.x, 0.f);
              const float h1 = fmaxf(fmaf(vt, za.y, ga.y) + ba.y, 0.f);
              const float h2 = fmaxf(fmaf(vt, za.z, ga.z) + ba.z, 0.f);
              const float h3 = fmaxf(fmaf(vt, za.w, ga.w) + ba.w, 0.f);
              l0 = fmaf(h0, ra.x, l0);
              l1 = fmaf(h1, ra.y, l1);
              l2 = fmaf(h2, ra.z, l2);
              l3 = fmaf(h3, ra.w, l3);
            }
          }
        }
        const float lg = (l0 + l1) + (l2 + l3);
        w_s[t] = lg;
        __syncthreads();
        // softmax stats, redundant per wave (no cross-wave barrier)
        float x0 = (lane       < L) ? w_s[lane]       : -1e30f;
        float x1 = (lane +  64 < L) ? w_s[lane +  64] : -1e30f;
        float x2 = (lane + 128 < L) ? w_s[lane + 128] : -1e30f;
        float x3 = (lane + 192 < L) ? w_s[lane + 192] : -1e30f;
        float m = fmaxf(fmaxf(x0, x1), fmaxf(x2, x3));
        #pragma unroll
        for (int d = 32; d > 0; d >>= 1) m = fmaxf(m, __shfl_xor(m, d));
        float s = __expf(x0 - m) + __expf(x1 - m) + __expf(x2 - m) + __expf(x3 - m);
        #pragma unroll
        for (int d = 32; d > 0; d >>= 1) s += __shfl_xor(s, d);
        const float w = (t < L) ? __expf(lg - m) / s : 0.f;
        __syncthreads();                           // w_s logits fully consumed
        w_s[t] = w;
        __syncthreads();
      }

      // u[k] = sum_tok w[tok] * h[tok][k], h recomputed; chunked over tokens
      {
        const int base = ch_u * 128;
        const int n = min(128, max(0, L - base));  // wave-uniform trip count
        float acc0 = 0.f, acc1 = 0.f;
        int i = 0;
        for (; i + 4 <= n; i += 4) {
          const int tk = base + i;
          const float h0 = fmaxf(fmaf(val_l[tk],     zk_u, We1[id_l[tk]     * EH + k_u]) + bk_u, 0.f);
          const float h1 = fmaxf(fmaf(val_l[tk + 1], zk_u, We1[id_l[tk + 1] * EH + k_u]) + bk_u, 0.f);
          const float h2 = fmaxf(fmaf(val_l[tk + 2], zk_u, We1[id_l[tk + 2] * EH + k_u]) + bk_u, 0.f);
          const float h3 = fmaxf(fmaf(val_l[tk + 3], zk_u, We1[id_l[tk + 3] * EH + k_u]) + bk_u, 0.f);
          acc0 = fmaf(w_s[tk],     h0, acc0);
          acc1 = fmaf(w_s[tk + 1], h1, acc1);
          acc0 = fmaf(w_s[tk + 2], h2, acc0);
          acc1 = fmaf(w_s[tk + 3], h3, acc1);
        }
        for (; i < n; ++i) {
          const int tk = base + i;
          const float hv = fmaxf(fmaf(val_l[tk], zk_u, We1[id_l[tk] * EH + k_u]) + bk_u, 0.f);
          acc0 = fmaf(w_s[tk], hv, acc0);
        }
        part2[ch_u][k_u] = acc0 + acc1;
      }
      __syncthreads();
      if (t < EH) u_s[t] = part2[0][t] + part2[1][t];
      __syncthreads();

      // attended = u @ We2 + be2 : 4 k-quarters per output col
      {
        const int e  = t & 63;
        const int kq = t >> 6;
        const float* __restrict__ col = We2 + e;
        const int k0 = kq * 32;
        float a0 = 0.f, a1 = 0.f;
        #pragma unroll
        for (int k = 0; k < 32; k += 2) {
          a0 = fmaf(u_s[k0 + k],     col[(k0 + k)     * E], a0);
          a1 = fmaf(u_s[k0 + k + 1], col[(k0 + k + 1) * E], a1);
        }
        red_s[t] = a0 + a1;
      }
      __syncthreads();
      if (t < E)
        att_s[t] = (red_s[t] + red_s[64 + t]) + (red_s[128 + t] + red_s[192 + t]) + be2[t];
      __syncthreads();

      // gates[t] = att @ Wih[:,t] (+ qt @ Whh[:,t]) + biases  (r3-verified)
      {
        float g0 = 0.f, g1 = 0.f, g2 = 0.f, g3 = 0.f;
        for (int e = 0; e < E; e += 4) {
          const float4 a = *(const float4*)(att_s + e);
          g0 = fmaf(a.x, Wih[(e)     * (4 * H) + t], g0);
          g1 = fmaf(a.y, Wih[(e + 1) * (4 * H) + t], g1);
          g2 = fmaf(a.z, Wih[(e + 2) * (4 * H) + t], g2);
          g3 = fmaf(a.w, Wih[(e + 3) * (4 * H) + t], g3);
        }
        if (it > 0) {
          for (int h = 0; h < H; h += 4) {
            const float4 q = *(const float4*)(qt_s + h);
            g0 = fmaf(q.x, Whh[(h)     * (4 * H) + t], g0);
            g1 = fmaf(q.y, Whh[(h + 1) * (4 * H) + t], g1);
            g2 = fmaf(q.z, Whh[(h + 2) * (4 * H) + t], g2);
            g3 = fmaf(q.w, Whh[(h + 3) * (4 * H) + t], g3);
          }
        }
        gates_s[t] = bih[t] + bhh[t] + (g0 + g1) + (g2 + g3);
      }
      __syncthreads();
      if (t < H) {
        const float ig = gates_s[t];
        const float fg = gates_s[H + t];
        const float gg = gates_s[2 * H + t];
        const float og = gates_s[3 * H + t];
        float c = ct_s[t];
        c = fsig(fg) * c + fsig(ig) * ftanh(gg);
        ct_s[t] = c;
        qt_s[t] = fsig(og) * ftanh(c);
      }
      __syncthreads();
    }
  }

  // ---------------- phase 3: DuelingNet (r3-verified, 256 threads) --------
  {
    float x0 = 0.f, x1 = 0.f, x2 = 0.f, x3 = 0.f;
    for (int k = 0; k < E; k += 4) {
      const float4 a = *(const float4*)(att_s + k);
      x0 = fmaf(a.x, Ws1[(k)     * SHD + t], x0);
      x1 = fmaf(a.y, Ws1[(k + 1) * SHD + t], x1);
      x2 = fmaf(a.z, Ws1[(k + 2) * SHD + t], x2);
      x3 = fmaf(a.w, Ws1[(k + 3) * SHD + t], x3);
    }
    for (int k = 0; k < H; k += 4) {
      const float4 q = *(const float4*)(qt_s + k);
      x0 = fmaf(q.x, Ws1[(E + k)     * SHD + t], x0);
      x1 = fmaf(q.y, Ws1[(E + k + 1) * SHD + t], x1);
      x2 = fmaf(q.z, Ws1[(E + k + 2) * SHD + t], x2);
      x3 = fmaf(q.w, Ws1[(E + k + 3) * SHD + t], x3);
    }
    t1_s[t] = fmaxf(bs1[t] + (x0 + x1) + (x2 + x3), 0.f);
  }
  __syncthreads();
  if (t < SD) {
    float x0 = 0.f, x1 = 0.f, x2 = 0.f, x3 = 0.f;
    for (int k = 0; k < SHD; k += 4) {
      const float4 a = *(const float4*)(t1_s + k);
      x0 = fmaf(a.x, Ws2[(k)     * SD + t], x0);
      x1 = fmaf(a.y, Ws2[(k + 1) * SD + t], x1);
      x2 = fmaf(a.z, Ws2[(k + 2) * SD + t], x2);
      x3 = fmaf(a.w, Ws2[(k + 3) * SD + t], x3);
    }
    sh_s[t] = fmaxf(bs2[t] + (x0 + x1) + (x2 + x3), 0.f);
  }
  __syncthreads();
  if (t < SD) {
    float x0 = 0.f, x1 = 0.f, x2 = 0.f, x3 = 0.f;
    for (int k = 0; k < SD; k += 4) {
      const float4 a = *(const float4*)(sh_s + k);
      x0 = fmaf(a.x, Wp1[(k)     * SD + t], x0);
      x1 = fmaf(a.y, Wp1[(k + 1) * SD + t], x1);
      x2 = fmaf(a.z, Wp1[(k + 2) * SD + t], x2);
      x3 = fmaf(a.w, Wp1[(k + 3) * SD + t], x3);
    }
    a1_s[t] = fmaxf(bp1[t] + (x0 + x1) + (x2 + x3), 0.f);
  } else {
    const int tt = t - SD;
    float x0 = 0.f, x1 = 0.f, x2 = 0.f, x3 = 0.f;
    for (int k = 0; k < SD; k += 4) {
      const float4 a = *(const float4*)(sh_s + k);
      x0 = fmaf(a.x, Wv1[(k)     * SD + tt], x0);
      x1 = fmaf(a.y, Wv1[(k + 1) * SD + tt], x1);
      x2 = fmaf(a.z, Wv1[(k + 2) * SD + tt], x2);
      x3 = fmaf(a.w, Wv1[(k + 3) * SD + tt], x3);
    }
    v1_s[tt] = fmaxf(bv1[tt] + (x0 + x1) + (x2 + x3), 0.f);
  }
  __syncthreads();
  if (wid == 1) {   // v = v1 @ Wv2 + bv2 (wave 1; wave 0 has adv2 extra col)
    float vv = fmaf(v1_s[lane], Wv2[lane], v1_s[lane + 64] * Wv2[lane + 64]);
    #pragma unroll
    for (int d = 32; d > 0; d >>= 1) vv += __shfl_xor(vv, d);
    if (lane == 0) v_scalar = vv + bv2[0];
  }
  // adv: one column per thread (+ col 256 on thread 0)
  float x0 = 0.f, x1 = 0.f, x2 = 0.f, x3 = 0.f;
  for (int k = 0; k < SD; k += 4) {
    const float4 a = *(const float4*)(a1_s + k);
    x0 = fmaf(a.x, Wp2[(k)     * NA + t], x0);
    x1 = fmaf(a.y, Wp2[(k + 1) * NA + t], x1);
    x2 = fmaf(a.z, Wp2[(k + 2) * NA + t], x2);
    x3 = fmaf(a.w, Wp2[(k + 3) * NA + t], x3);
  }
  const float adv = bp2[t] + (x0 + x1) + (x2 + x3);
  float adv2 = 0.f;
  if (t == 0) {
    float y0 = 0.f, y1 = 0.f, y2 = 0.f, y3 = 0.f;
    for (int k = 0; k < SD; k += 4) {
      const float4 a = *(const float4*)(a1_s + k);
      y0 = fmaf(a.x, Wp2[(k)     * NA + (NA - 1)], y0);
      y1 = fmaf(a.y, Wp2[(k + 1) * NA + (NA - 1)], y1);
      y2 = fmaf(a.z, Wp2[(k + 2) * NA + (NA - 1)], y2);
      y3 = fmaf(a.w, Wp2[(k + 3) * NA + (NA - 1)], y3);
    }
    adv2 = bp2[NA - 1] + (y0 + y1) + (y2 + y3);
  }
  float ssum = adv + adv2;
  #pragma unroll
  for (int d = 32; d > 0; d >>= 1) ssum += __shfl_xor(ssum, d);
  if (lane == 0) wred[wid] = ssum;
  __syncthreads();
  const float mean = ((wred[0] + wred[1]) + (wred[2] + wred[3])) * (1.f / (float)NA);
  const float vv = v_scalar;
  out[b * NA + t] = vv + adv - mean;
  if (t == 0) out[b * NA + (NA - 1)] = vv + adv2 - mean;
}

}  // namespace

extern "C" void kernel_launch(void* const* d_in, const int* in_sizes, int n_in,
                              void* d_out, int out_size, void* d_ws, size_t ws_size,
                              hipStream_t stream) {
  const float* state    = (const float*)d_in[0];
  const int*   acquired = (const int*)d_in[1];
  const float* We1 = (const float*)d_in[2];
  const float* be1 = (const float*)d_in[3];
  const float* We2 = (const float*)d_in[4];
  const float* be2 = (const float*)d_in[5];
  const float* Wih = (const float*)d_in[6];
  const float* Whh = (const float*)d_in[7];
  const float* bih = (const float*)d_in[8];
  const float* bhh = (const float*)d_in[9];
  const float* Ws1 = (const float*)d_in[10];
  const float* bs1 = (const float*)d_in[11];
  const float* Ws2 = (const float*)d_in[12];
  const float* bs2 = (const float*)d_in[13];
  const float* Wp1 = (const float*)d_in[14];
  const float* bp1 = (const float*)d_in[15];
  const float* Wp2 = (const float*)d_in[16];
  const float* bp2 = (const float*)d_in[17];
  const float* Wv1 = (const float*)d_in[18];
  const float* bv1 = (const float*)d_in[19];
  const float* Wv2 = (const float*)d_in[20];
  const float* bv2 = (const float*)d_in[21];
  float* out = (float*)d_out;

  const int Bn = in_sizes[0] / NF;   // 2048
  hipLaunchKernelGGL(seqnet, dim3(Bn), dim3(256), 0, stream,
                     state, acquired, We1, be1, We2, be2, Wih, Whh, bih, bhh,
                     Ws1, bs1, Ws2, bs2, Wp1, bp1, Wp2, bp2, Wv1, bv1, Wv2, bv2,
                     out);
}

// Round 14
// 173.659 us; speedup vs baseline: 6.2949x; 3.5785x over previous
//
#include <hip/hip_runtime.h>
#include <math.h>

namespace {

constexpr int NF   = 256;   // n_feature / tokens
constexpr int EH   = 128;   // embedder hidden
constexpr int E    = 64;    // embedded dim
constexpr int H    = 64;    // lstm size
constexpr int SHD  = 256;   // shared hidden
constexpr int SD   = 128;   // shared dim
constexpr int NA   = 257;   // n_action
constexpr int NSHUF = 4;

__device__ __forceinline__ float fsig(float x) {
  return 1.f / (1.f + __expf(-x));
}
__device__ __forceinline__ float ftanh(float x) {
  return 1.f - 2.f / (__expf(2.f * x) + 1.f);
}

// ONE WAVE PER ROW, ZERO BARRIERS. All cross-lane via shfl; LDS used only as
// a wave-private scratchpad (same-wave DS ops complete in order -> no
// __syncthreads needed). Factored attention (r11-r13-verified algebra):
//   logits = h.(We2 qt) (+const, cancels in softmax)
//   attended = (sum_t w_t h_t) @ We2 + be2          (since sum w = 1)
// h recomputed on the fly: h[tok][k] = relu(val*We1[0][k] + We1[id][k] + be1[k]).
// Token->group map tok = 4*i + g balances the 4 sixteen-lane groups for any L.
__global__ __launch_bounds__(64)
void seqnet(
    const float* __restrict__ state, const int* __restrict__ acquired,
    const float* __restrict__ We1, const float* __restrict__ be1,
    const float* __restrict__ We2, const float* __restrict__ be2,
    const float* __restrict__ Wih, const float* __restrict__ Whh,
    const float* __restrict__ bih, const float* __restrict__ bhh,
    const float* __restrict__ Ws1, const float* __restrict__ bs1,
    const float* __restrict__ Ws2, const float* __restrict__ bs2,
    const float* __restrict__ Wp1, const float* __restrict__ bp1,
    const float* __restrict__ Wp2, const float* __restrict__ bp2,
    const float* __restrict__ Wv1, const float* __restrict__ bv1,
    const float* __restrict__ Wv2, const float* __restrict__ bv2,
    float* __restrict__ out)
{
  const int row = blockIdx.x;
  const int l   = threadIdx.x;    // 0..63 (one wave)
  const int g   = l >> 4;         // token group 0..3
  const int sub = l & 15;         // k-slice owner within group
  const int kbase = sub * 8;      // owns k = kbase..kbase+7

  __shared__ int   id_s[NF];
  __shared__ __align__(16) float val_s[NF];
  __shared__ __align__(16) float w_s[NF];
  __shared__ __align__(16) float rv_s[EH];
  __shared__ __align__(16) float u_s[EH];
  __shared__ __align__(16) float enc_s[EH];   // att[0:64] | qt[64:128]
  __shared__ __align__(16) float t1_s[SHD];
  __shared__ __align__(16) float sh_s[SD];
  __shared__ __align__(16) float a1_s[SD];
  __shared__ __align__(16) float v1_s[SD];

  // ---------------- phase 0: closed-form "argsort" (wave-local) -----------
  const int* __restrict__ arow = acquired + row * NF;
  #pragma unroll
  for (int j = 0; j < 4; ++j) { id_s[l + 64 * j] = 0; val_s[l + 64 * j] = 0.f; }
  int aiv[4];
  unsigned long long m0, m1, m2, m3;
  aiv[0] = (arow[l]       != 0); m0 = __ballot(aiv[0]);
  aiv[1] = (arow[64 + l]  != 0); m1 = __ballot(aiv[1]);
  aiv[2] = (arow[128 + l] != 0); m2 = __ballot(aiv[2]);
  aiv[3] = (arow[192 + l] != 0); m3 = __ballot(aiv[3]);
  const int pc0 = __popcll(m0), pc1 = __popcll(m1);
  const int pc2 = __popcll(m2), pc3 = __popcll(m3);
  const int L = pc0 + pc1 + pc2 + pc3;
  {  // rank = # acquired with index > tok (descending stable order)
    const int suf1 = pc1 + pc2 + pc3, suf2 = pc2 + pc3, suf3 = pc3;
    if (aiv[0]) { const int r = (int)__popcll((m0 >> l) >> 1) + suf1;
      id_s[r] = l + 1;       val_s[r] = state[row * NF + l]; }
    if (aiv[1]) { const int r = (int)__popcll((m1 >> l) >> 1) + suf2;
      id_s[r] = 64 + l + 1;  val_s[r] = state[row * NF + 64 + l]; }
    if (aiv[2]) { const int r = (int)__popcll((m2 >> l) >> 1) + suf3;
      id_s[r] = 128 + l + 1; val_s[r] = state[row * NF + 128 + l]; }
    if (aiv[3]) { const int r = (int)__popcll((m3 >> l) >> 1);
      id_s[r] = 192 + l + 1; val_s[r] = state[row * NF + 192 + l]; }
  }

  float qt_r = 0.f, ct_r = 0.f;

  // hoisted per-lane h-recompute constants for k-slice [kbase, kbase+8)
  const float4 z0 = *(const float4*)(We1 + kbase);        // row 0 (val weight)
  const float4 z1 = *(const float4*)(We1 + kbase + 4);
  const float4 c0 = *(const float4*)(be1 + kbase);
  const float4 c1 = *(const float4*)(be1 + kbase + 4);

  if (L > 0) {
    const float invL = 1.f / (float)L;
    // group g owns tokens {4i+g}; trips within 1 of each other for any L
    const int ntok = (L > g) ? ((L - g + 3) >> 2) : 0;
    for (int it = 0; it < NSHUF; ++it) {
      if (it == 0) {
        // qt == 0 -> uniform softmax over first L tokens
        #pragma unroll
        for (int j = 0; j < 4; ++j) w_s[l + 64 * j] = invL;
      } else {
        // rv = We2 @ qt : lane computes rv[l], rv[64+l]
        {
          const float4* __restrict__ r0 = (const float4*)(We2 + l * E);
          const float4* __restrict__ r1 = (const float4*)(We2 + (64 + l) * E);
          float a0 = 0.f, a1 = 0.f;
          #pragma unroll
          for (int j = 0; j < 16; ++j) {
            const float4 x0 = r0[j], x1 = r1[j];
            float qv;
            qv = __shfl(qt_r, 4 * j);     a0 = fmaf(x0.x, qv, a0); a1 = fmaf(x1.x, qv, a1);
            qv = __shfl(qt_r, 4 * j + 1); a0 = fmaf(x0.y, qv, a0); a1 = fmaf(x1.y, qv, a1);
            qv = __shfl(qt_r, 4 * j + 2); a0 = fmaf(x0.z, qv, a0); a1 = fmaf(x1.z, qv, a1);
            qv = __shfl(qt_r, 4 * j + 3); a0 = fmaf(x0.w, qv, a0); a1 = fmaf(x1.w, qv, a1);
          }
          rv_s[l] = a0; rv_s[64 + l] = a1;
        }
        const float4 ra = *(const float4*)(rv_s + kbase);
        const float4 rb = *(const float4*)(rv_s + kbase + 4);
        // logits: group g, token 4i+g; 16 lanes cover k; 4-step butterfly
        for (int i = 0; i < ntok; ++i) {
          const int tok = 4 * i + g;
          const int   idt = id_s[tok];
          const float vt  = val_s[tok];
          const float4* __restrict__ gr = (const float4*)(We1 + idt * EH + kbase);
          const float4 ga = gr[0], gb = gr[1];
          float h, p;
          h = fmaxf(fmaf(vt, z0.x, ga.x) + c0.x, 0.f); p = h * ra.x;
          h = fmaxf(fmaf(vt, z0.y, ga.y) + c0.y, 0.f); p = fmaf(h, ra.y, p);
          h = fmaxf(fmaf(vt, z0.z, ga.z) + c0.z, 0.f); p = fmaf(h, ra.z, p);
          h = fmaxf(fmaf(vt, z0.w, ga.w) + c0.w, 0.f); p = fmaf(h, ra.w, p);
          h = fmaxf(fmaf(vt, z1.x, gb.x) + c1.x, 0.f); p = fmaf(h, rb.x, p);
          h = fmaxf(fmaf(vt, z1.y, gb.y) + c1.y, 0.f); p = fmaf(h, rb.y, p);
          h = fmaxf(fmaf(vt, z1.z, gb.z) + c1.z, 0.f); p = fmaf(h, rb.z, p);
          h = fmaxf(fmaf(vt, z1.w, gb.w) + c1.w, 0.f); p = fmaf(h, rb.w, p);
          p += __shfl_xor(p, 1); p += __shfl_xor(p, 2);
          p += __shfl_xor(p, 4); p += __shfl_xor(p, 8);
          if (sub == 0) w_s[tok] = p;
        }
        // softmax over w_s[0..L), 4 tokens per lane
        float x0 = w_s[l], x1 = w_s[64 + l], x2 = w_s[128 + l], x3 = w_s[192 + l];
        x0 = (l < L)       ? x0 : -1e30f;
        x1 = (64 + l < L)  ? x1 : -1e30f;
        x2 = (128 + l < L) ? x2 : -1e30f;
        x3 = (192 + l < L) ? x3 : -1e30f;
        float mx = fmaxf(fmaxf(x0, x1), fmaxf(x2, x3));
        #pragma unroll
        for (int d = 32; d > 0; d >>= 1) mx = fmaxf(mx, __shfl_xor(mx, d));
        const float e0 = (l < L)       ? __expf(x0 - mx) : 0.f;
        const float e1 = (64 + l < L)  ? __expf(x1 - mx) : 0.f;
        const float e2 = (128 + l < L) ? __expf(x2 - mx) : 0.f;
        const float e3 = (192 + l < L) ? __expf(x3 - mx) : 0.f;
        float s = (e0 + e1) + (e2 + e3);
        #pragma unroll
        for (int d = 32; d > 0; d >>= 1) s += __shfl_xor(s, d);
        const float inv = 1.f / s;
        w_s[l]       = e0 * inv;
        w_s[64 + l]  = e1 * inv;
        w_s[128 + l] = e2 * inv;
        w_s[192 + l] = e3 * inv;
      }

      // u[k] = sum_tok w*h : per-lane 8-k accum over group's tokens
      float4 ua{0, 0, 0, 0}, ub{0, 0, 0, 0};
      for (int i = 0; i < ntok; ++i) {
        const int tok = 4 * i + g;
        const int   idt = id_s[tok];
        const float vt  = val_s[tok];
        const float wt  = w_s[tok];
        const float4* __restrict__ gr = (const float4*)(We1 + idt * EH + kbase);
        const float4 ga = gr[0], gb = gr[1];
        float h;
        h = fmaxf(fmaf(vt, z0.x, ga.x) + c0.x, 0.f); ua.x = fmaf(wt, h, ua.x);
        h = fmaxf(fmaf(vt, z0.y, ga.y) + c0.y, 0.f); ua.y = fmaf(wt, h, ua.y);
        h = fmaxf(fmaf(vt, z0.z, ga.z) + c0.z, 0.f); ua.z = fmaf(wt, h, ua.z);
        h = fmaxf(fmaf(vt, z0.w, ga.w) + c0.w, 0.f); ua.w = fmaf(wt, h, ua.w);
        h = fmaxf(fmaf(vt, z1.x, gb.x) + c1.x, 0.f); ub.x = fmaf(wt, h, ub.x);
        h = fmaxf(fmaf(vt, z1.y, gb.y) + c1.y, 0.f); ub.y = fmaf(wt, h, ub.y);
        h = fmaxf(fmaf(vt, z1.z, gb.z) + c1.z, 0.f); ub.z = fmaf(wt, h, ub.z);
        h = fmaxf(fmaf(vt, z1.w, gb.w) + c1.w, 0.f); ub.w = fmaf(wt, h, ub.w);
      }
      #pragma unroll
      for (int d = 16; d <= 32; d <<= 1) {   // cross-group: same sub = same k
        ua.x += __shfl_xor(ua.x, d); ua.y += __shfl_xor(ua.y, d);
        ua.z += __shfl_xor(ua.z, d); ua.w += __shfl_xor(ua.w, d);
        ub.x += __shfl_xor(ub.x, d); ub.y += __shfl_xor(ub.y, d);
        ub.z += __shfl_xor(ub.z, d); ub.w += __shfl_xor(ub.w, d);
      }
      if (l < 16) {
        *(float4*)(u_s + l * 8)     = ua;
        *(float4*)(u_s + l * 8 + 4) = ub;
      }

      // attended[l] = sum_k u[k]*We2[k][l] + be2[l]   (coalesced columns)
      {
        float a0 = 0.f, a1 = 0.f, a2 = 0.f, a3 = 0.f;
        #pragma unroll 4
        for (int k = 0; k < EH; k += 4) {
          a0 = fmaf(u_s[k],     We2[(k)     * E + l], a0);
          a1 = fmaf(u_s[k + 1], We2[(k + 1) * E + l], a1);
          a2 = fmaf(u_s[k + 2], We2[(k + 2) * E + l], a2);
          a3 = fmaf(u_s[k + 3], We2[(k + 3) * E + l], a3);
        }
        enc_s[l] = (a0 + a1) + (a2 + a3) + be2[l];
      }

      // gates: lane l owns cells l -> cols l, 64+l, 128+l, 192+l (i,f,g,o)
      float gi = 0.f, gf = 0.f, gg = 0.f, go = 0.f;
      #pragma unroll 2
      for (int e = 0; e < E; ++e) {
        const float av = enc_s[e];
        const float* __restrict__ wc = Wih + e * 256;
        gi = fmaf(av, wc[l],       gi);
        gf = fmaf(av, wc[64 + l],  gf);
        gg = fmaf(av, wc[128 + l], gg);
        go = fmaf(av, wc[192 + l], go);
      }
      if (it > 0) {
        #pragma unroll 2
        for (int e = 0; e < E; ++e) {
          const float qv = __shfl(qt_r, e);
          const float* __restrict__ wc = Whh + e * 256;
          gi = fmaf(qv, wc[l],       gi);
          gf = fmaf(qv, wc[64 + l],  gf);
          gg = fmaf(qv, wc[128 + l], gg);
          go = fmaf(qv, wc[192 + l], go);
        }
      }
      gi += bih[l]       + bhh[l];
      gf += bih[64 + l]  + bhh[64 + l];
      gg += bih[128 + l] + bhh[128 + l];
      go += bih[192 + l] + bhh[192 + l];
      ct_r = fsig(gf) * ct_r + fsig(gi) * ftanh(gg);
      qt_r = fsig(go) * ftanh(ct_r);
    }
    enc_s[64 + l] = qt_r;
  } else {
    enc_s[l] = 0.f; enc_s[64 + l] = 0.f;   // reference zeroes encoded
  }

  // ---------------- phase 3: DuelingNet (wave-local, coalesced) -----------
  {  // t1 = relu(enc @ Ws1 + bs1): 4 cols per lane
    float t0 = 0.f, t1 = 0.f, t2 = 0.f, t3 = 0.f;
    #pragma unroll 2
    for (int k = 0; k < EH; ++k) {
      const float ev = enc_s[k];
      const float* __restrict__ wr = Ws1 + k * SHD;
      t0 = fmaf(ev, wr[l],       t0);
      t1 = fmaf(ev, wr[64 + l],  t1);
      t2 = fmaf(ev, wr[128 + l], t2);
      t3 = fmaf(ev, wr[192 + l], t3);
    }
    t1_s[l]       = fmaxf(t0 + bs1[l],       0.f);
    t1_s[64 + l]  = fmaxf(t1 + bs1[64 + l],  0.f);
    t1_s[128 + l] = fmaxf(t2 + bs1[128 + l], 0.f);
    t1_s[192 + l] = fmaxf(t3 + bs1[192 + l], 0.f);
  }
  {  // sh = relu(t1 @ Ws2 + bs2): 2 cols per lane
    float s0 = 0.f, s1 = 0.f;
    #pragma unroll 2
    for (int k = 0; k < SHD; ++k) {
      const float tv = t1_s[k];
      s0 = fmaf(tv, Ws2[k * SD + l],      s0);
      s1 = fmaf(tv, Ws2[k * SD + 64 + l], s1);
    }
    sh_s[l]      = fmaxf(s0 + bs2[l],      0.f);
    sh_s[64 + l] = fmaxf(s1 + bs2[64 + l], 0.f);
  }
  {  // a1 = relu(sh@Wp1+bp1), v1 = relu(sh@Wv1+bv1): 2 cols each per lane
    float p0 = 0.f, p1 = 0.f, q0 = 0.f, q1 = 0.f;
    #pragma unroll 2
    for (int k = 0; k < SD; ++k) {
      const float sv = sh_s[k];
      p0 = fmaf(sv, Wp1[k * SD + l],      p0);
      p1 = fmaf(sv, Wp1[k * SD + 64 + l], p1);
      q0 = fmaf(sv, Wv1[k * SD + l],      q0);
      q1 = fmaf(sv, Wv1[k * SD + 64 + l], q1);
    }
    a1_s[l]      = fmaxf(p0 + bp1[l],      0.f);
    a1_s[64 + l] = fmaxf(p1 + bp1[64 + l], 0.f);
    v1_s[l]      = fmaxf(q0 + bv1[l],      0.f);
    v1_s[64 + l] = fmaxf(q1 + bv1[64 + l], 0.f);
  }
  // adv cols l+64j (4 per lane)
  float a0 = 0.f, a1 = 0.f, a2 = 0.f, a3 = 0.f;
  #pragma unroll 2
  for (int k = 0; k < SD; ++k) {
    const float av = a1_s[k];
    const float* __restrict__ wr = Wp2 + k * NA;
    a0 = fmaf(av, wr[l],       a0);
    a1 = fmaf(av, wr[64 + l],  a1);
    a2 = fmaf(av, wr[128 + l], a2);
    a3 = fmaf(av, wr[192 + l], a3);
  }
  a0 += bp2[l]; a1 += bp2[64 + l]; a2 += bp2[128 + l]; a3 += bp2[192 + l];
  // adv col 256: distributed dot (2 k per lane) + butterfly
  float c4 = fmaf(a1_s[2 * l], Wp2[(2 * l) * NA + 256],
                  a1_s[2 * l + 1] * Wp2[(2 * l + 1) * NA + 256]);
  #pragma unroll
  for (int d = 32; d > 0; d >>= 1) c4 += __shfl_xor(c4, d);
  const float adv4 = c4 + bp2[256];
  // v scalar
  float vv = fmaf(v1_s[l], Wv2[l], v1_s[64 + l] * Wv2[64 + l]);
  #pragma unroll
  for (int d = 32; d > 0; d >>= 1) vv += __shfl_xor(vv, d);
  const float v = vv + bv2[0];
  // mean over 257 cols
  float ss = (a0 + a1) + (a2 + a3);
  #pragma unroll
  for (int d = 32; d > 0; d >>= 1) ss += __shfl_xor(ss, d);
  const float mean = (ss + adv4) * (1.f / (float)NA);

  const float base = v - mean;
  float* __restrict__ orow = out + row * NA;
  orow[l]       = base + a0;
  orow[64 + l]  = base + a1;
  orow[128 + l] = base + a2;
  orow[192 + l] = base + a3;
  if (l == 0) orow[256] = base + adv4;
}

}  // namespace

extern "C" void kernel_launch(void* const* d_in, const int* in_sizes, int n_in,
                              void* d_out, int out_size, void* d_ws, size_t ws_size,
                              hipStream_t stream) {
  const float* state    = (const float*)d_in[0];
  const int*   acquired = (const int*)d_in[1];
  const float* We1 = (const float*)d_in[2];
  const float* be1 = (const float*)d_in[3];
  const float* We2 = (const float*)d_in[4];
  const float* be2 = (const float*)d_in[5];
  const float* Wih = (const float*)d_in[6];
  const float* Whh = (const float*)d_in[7];
  const float* bih = (const float*)d_in[8];
  const float* bhh = (const float*)d_in[9];
  const float* Ws1 = (const float*)d_in[10];
  const float* bs1 = (const float*)d_in[11];
  const float* Ws2 = (const float*)d_in[12];
  const float* bs2 = (const float*)d_in[13];
  const float* Wp1 = (const float*)d_in[14];
  const float* bp1 = (const float*)d_in[15];
  const float* Wp2 = (const float*)d_in[16];
  const float* bp2 = (const float*)d_in[17];
  const float* Wv1 = (const float*)d_in[18];
  const float* bv1 = (const float*)d_in[19];
  const float* Wv2 = (const float*)d_in[20];
  const float* bv2 = (const float*)d_in[21];
  float* out = (float*)d_out;

  const int Bn = in_sizes[0] / NF;   // 2048 rows; one 64-thread wave per row
  hipLaunchKernelGGL(seqnet, dim3(Bn), dim3(64), 0, stream,
                     state, acquired, We1, be1, We2, be2, Wih, Whh, bih, bhh,
                     Ws1, bs1, Ws2, bs2, Wp1, bp1, Wp2, bp2, Wv1, bv1, Wv2, bv2,
                     out);
}